// Round 6
// baseline (159.771 us; speedup 1.0000x reference)
//
#include <hip/hip_runtime.h>
#include <hip/hip_bf16.h>

// Problem constants
#define B_   16
#define C_   256
#define T_   2048
#define PS   12
#define NNEG 15
#define OFFS 16
#define COPIES 16

// Derived
#define M_GEMM (B_ * T_)        // 32768 rows (b,t)
#define N_GEMM (C_ * PS)        // 3072 cols (j = i*256 + o)
#define K_GEMM C_               // 256
#define NPRED 6225408           // sum_i (2032-i)*256
#define NLAB  389088

// b-slicing: producer/consumer pairs sized so zp slice stays L3-resident
#define BSLICE 8                // b's per slice
#define NSLICE (B_ / BSLICE)    // 2

using bf16 = __hip_bfloat16;
typedef __attribute__((ext_vector_type(4))) float f32x4;
typedef __attribute__((ext_vector_type(8))) short bf16x8;

#define WAITVM(n) asm volatile("s_waitcnt vmcnt(" #n ")" ::: "memory")
#define GLL(src, dst)                                                        \
    __builtin_amdgcn_global_load_lds(                                        \
        (const __attribute__((address_space(1))) void*)(src),                \
        (__attribute__((address_space(3))) void*)(dst), 16, 0, 0)

// ---------------------------------------------------------------- transpose z
// z[b][c][t] f32  ->  zT[b][t][c] bf16
__global__ __launch_bounds__(256) void transpose_z(const float* __restrict__ z,
                                                   bf16* __restrict__ zT) {
    __shared__ float tile[32][33];
    int t0 = blockIdx.x * 32, c0 = blockIdx.y * 32, b = blockIdx.z;
    int col = threadIdx.x & 31, r = threadIdx.x >> 5;
    for (int rr = 0; rr < 4; ++rr) {
        int row = r + rr * 8;
        tile[row][col] = z[(size_t)(b * C_ + c0 + row) * T_ + t0 + col];
    }
    __syncthreads();
    for (int rr = 0; rr < 4; ++rr) {
        int row = r + rr * 8;
        zT[(size_t)(b * T_ + t0 + row) * C_ + c0 + col] =
            __float2bfloat16(tile[col][row]);
    }
}

// ---------------------------------------------------------------- pack weight
// w[c][o][i] f32 -> wTb[j][c] bf16 with j = i*256 + o
__global__ __launch_bounds__(256) void pack_w(const float* __restrict__ w,
                                              bf16* __restrict__ wTb) {
    int gid = blockIdx.x * 256 + threadIdx.x;
    int j = gid >> 8, c = gid & 255;
    int o = j & 255, i = j >> 8;
    wTb[gid] = __float2bfloat16(w[(size_t)c * (C_ * PS) + o * PS + i]);
}

// ---------------------------------------------------------------- z_pred GEMM
// 128x128 tile, 4 waves (2x2), BK=32, depth-3 counted-vmcnt LDS pipeline.
// Internals unchanged from round 4; b-sliced: covers rows of BSLICE b's.
// zp slice indexed by LOCAL b (b - b_base) so a 100MB buffer is reused.
#define EPAD 136

__global__ __launch_bounds__(256) void gemm_zpred(const bf16* __restrict__ zT,
                                                  const bf16* __restrict__ wTb,
                                                  const float* __restrict__ bias,
                                                  bf16* __restrict__ zp,
                                                  int b_base) {
    __shared__ __align__(16) char smem[49152];
    bf16* lE = (bf16*)smem;

    // bijective XCD swizzle: grid = 3072 = 8 * 384
    int bid = (blockIdx.x & 7) * 384 + (blockIdx.x >> 3);
    int bn = bid % (N_GEMM / 128);   // 24
    int bm = bid / (N_GEMM / 128);   // 128
    int tid = threadIdx.x;
    int wid = tid >> 6, lane = tid & 63;
    int ln15 = lane & 15, kg = lane >> 4;
    int wm = (wid & 1) * 64, wn = (wid >> 1) * 64;
    int row0 = b_base * T_ + bm * 128;   // global (b,t) row
    int col0 = bn * 128;
    int i_step = col0 >> 8;
    int o0 = col0 & 255;

    int gsw = ((lane & 3) ^ ((lane >> 3) & 3)) * 8;
    int srow = wid * 16 + (lane >> 2);
    const bf16* srcA = zT + (size_t)(row0 + srow) * 256 + gsw;
    const bf16* srcB = wTb + (size_t)(col0 + srow) * 256 + gsw;

    int offA[4], offB[4];
#pragma unroll
    for (int mi = 0; mi < 4; ++mi) {
        int r = wm + mi * 16 + ln15;
        offA[mi] = r * 64 + ((kg ^ ((r >> 1) & 3)) * 16);
    }
#pragma unroll
    for (int ni = 0; ni < 4; ++ni) {
        int c = wn + ni * 16 + ln15;
        offB[ni] = 8192 + c * 64 + ((kg ^ ((c >> 1) & 3)) * 16);
    }

    f32x4 acc[4][4] = {};

#define STAGE(t, slot_base)                                                  \
    {                                                                        \
        char* d = smem + (slot_base) + wid * 1024;                           \
        const bf16* sa = srcA + (t) * 32;                                    \
        const bf16* sb2 = srcB + (t) * 32;                                   \
        GLL(sa, d);                                                          \
        GLL(sa + 64 * 256, d + 4096);                                        \
        GLL(sb2, d + 8192);                                                  \
        GLL(sb2 + 64 * 256, d + 12288);                                      \
    }

#define TILE_BODY(slot_base, VMN)                                            \
    {                                                                        \
        WAITVM(VMN);                                                         \
        __builtin_amdgcn_s_barrier();                                        \
        const char* sb = smem + (slot_base);                                 \
        bf16x8 af[4], bfr[4];                                                \
        _Pragma("unroll") for (int mi = 0; mi < 4; ++mi)                     \
            af[mi] = *(const bf16x8*)(sb + offA[mi]);                        \
        _Pragma("unroll") for (int ni = 0; ni < 4; ++ni)                     \
            bfr[ni] = *(const bf16x8*)(sb + offB[ni]);                       \
        asm volatile("s_waitcnt lgkmcnt(0)" ::: "memory");                   \
        __builtin_amdgcn_sched_barrier(0);                                   \
        __builtin_amdgcn_s_barrier();                                        \
        __builtin_amdgcn_s_setprio(1);                                       \
        _Pragma("unroll") for (int mi = 0; mi < 4; ++mi)                     \
            _Pragma("unroll") for (int ni = 0; ni < 4; ++ni)                 \
                acc[mi][ni] = __builtin_amdgcn_mfma_f32_16x16x32_bf16(       \
                    af[mi], bfr[ni], acc[mi][ni], 0, 0, 0);                  \
        __builtin_amdgcn_s_setprio(0);                                       \
    }

    STAGE(0, 0);
    STAGE(1, 16384);
    STAGE(2, 32768);  TILE_BODY(0, 8);
    STAGE(3, 0);      TILE_BODY(16384, 8);
    STAGE(4, 16384);  TILE_BODY(32768, 8);
    STAGE(5, 32768);  TILE_BODY(0, 8);
    STAGE(6, 0);      TILE_BODY(16384, 8);
    STAGE(7, 16384);  TILE_BODY(32768, 8);
                      TILE_BODY(0, 4);
                      TILE_BODY(16384, 0);

    __syncthreads();

    float bv[4];
#pragma unroll
    for (int ni = 0; ni < 4; ++ni) bv[ni] = bias[o0 + wn + ni * 16 + ln15];

#pragma unroll
    for (int mi = 0; mi < 4; ++mi)
#pragma unroll
        for (int ni = 0; ni < 4; ++ni) {
            int col_e = wn + ni * 16 + ln15;
#pragma unroll
            for (int r = 0; r < 4; ++r) {
                int row_e = wm + mi * 16 + kg * 4 + r;
                lE[row_e * EPAD + col_e] = __float2bfloat16(acc[mi][ni][r] + bv[ni]);
            }
        }

    __syncthreads();

#pragma unroll
    for (int e = 0; e < 8; ++e) {
        int row_e = e * 16 + (tid >> 4);
        int grow = row0 + row_e;
        int bl = (grow >> 11) - b_base;      // LOCAL b within slice
        int t = grow & (T_ - 1);
        int s = t + OFFS + i_step;
        if (s < T_) {
            bf16x8 v = *(const bf16x8*)&lE[row_e * EPAD + (tid & 15) * 8];
            *(bf16x8*)(zp + ((size_t)(bl * T_ + s) * PS + i_step) * 256 + o0 +
                       (tid & 15) * 8) = v;
        }
    }
#undef STAGE
#undef TILE_BODY
}

// ---------------------------------------------------------------- predictions
// Internals unchanged from round 5; b-sliced (zp indexed by local b).
__global__ __launch_bounds__(256) void predict_kernel(
    const bf16* __restrict__ zT, const bf16* __restrict__ zp,
    const int* __restrict__ neg, float* __restrict__ out, int b_base) {
    __shared__ __align__(16) char psm[131072];
    int tid = threadIdx.x;
    int wid = tid >> 6, lane = tid & 63;
    int ln15 = lane & 15, kg = lane >> 4;
    char* my = psm + wid * 32768;           // wave-private: 2 slots x 16KB
    int base_gi = (blockIdx.x * 4 + wid) * 8;   // within slice

    const char* zTb = (const char*)zT;
    const char* zpb = (const char*)zp;

    auto stage = [&](int it, int slot) {
        int gi = base_gi + it;
        int bl = gi / (T_ - OFFS);          // local b
        int b = b_base + bl;                // global b
        int s = OFFS + gi % (T_ - OFFS);
        int srcrow = 0;
        if (lane < 16) {
            if (lane == 0) srcrow = b * T_ + s;
            else srcrow = neg[b * (NNEG * T_) + (lane - 1) * T_ + s];
        }
        char* dst = my + slot * 16384;
        int half = lane >> 5;
        int g31 = lane & 31;
#pragma unroll
        for (int j = 0; j < 8; ++j) {
            int r0 = __shfl(srcrow, 2 * j);
            int r1 = __shfl(srcrow, 2 * j + 1);
            int row = half ? r1 : r0;
            int n = 2 * j + half;
            const char* src = zTb + (size_t)row * 512 + ((g31 ^ (n & 7)) << 4);
            GLL(src, dst + j * 1024);
        }
        size_t zoff = (size_t)(bl * T_ + s) * (PS * 512);   // LOCAL b
#pragma unroll
        for (int j = 0; j < 6; ++j) {
            int i0 = 2 * j + half;
            const char* src = zpb + zoff + i0 * 512 + ((g31 ^ (i0 & 7)) << 4);
            GLL(src, dst + 8192 + j * 1024);
        }
    };

    auto compute = [&](int it, int slot) {
        const char* sb = my + slot * 16384;
        int ii = ln15 < 12 ? ln15 : 0;
        bf16x8 af[8], bfr[8];
#pragma unroll
        for (int kk = 0; kk < 8; ++kk) {
            int g = kk * 4 + kg;
            af[kk] = *(const bf16x8*)(sb + ln15 * 512 + ((g ^ (ln15 & 7)) << 4));
            bfr[kk] = *(const bf16x8*)(sb + 8192 + ii * 512 + ((g ^ (ii & 7)) << 4));
        }
        asm volatile("s_waitcnt lgkmcnt(0)" ::: "memory");
        __builtin_amdgcn_sched_barrier(0);
        if (it + 2 < 8) stage(it + 2, slot);

        f32x4 acc = {0.f, 0.f, 0.f, 0.f};
#pragma unroll
        for (int kk = 0; kk < 8; ++kk)
            acc = __builtin_amdgcn_mfma_f32_16x16x32_bf16(af[kk], bfr[kk], acc,
                                                          0, 0, 0);

        int gi = base_gi + it;
        int b = b_base + gi / (T_ - OFFS);
        int s = OFFS + gi % (T_ - OFFS);
        int i = ln15;
        int imax = s - OFFS; if (imax > PS - 1) imax = PS - 1;
        if (i <= imax) {
            int t = s - OFFS - i;
            int base_i = 256 * ((T_ - OFFS) * i - (i * (i - 1)) / 2);
            float* o = out + base_i + (t * B_ + b) * COPIES + kg * 4;
            o[0] = acc[0]; o[1] = acc[1]; o[2] = acc[2]; o[3] = acc[3];
        }
    };

    stage(0, 0);
    stage(1, 1);
#pragma unroll
    for (int it = 0; it < 8; ++it) {
        if (it < 7) { WAITVM(14); }
        else        { WAITVM(0);  }
        compute(it, it & 1);
    }
}

// ---------------------------------------------------------------- launch
extern "C" void kernel_launch(void* const* d_in, const int* in_sizes, int n_in,
                              void* d_out, int out_size, void* d_ws, size_t ws_size,
                              hipStream_t stream) {
    const float* z    = (const float*)d_in[0];
    const float* w    = (const float*)d_in[1];
    const float* bias = (const float*)d_in[2];
    const int*   neg  = (const int*)d_in[3];
    float* out = (float*)d_out;

    char* ws = (char*)d_ws;
    // zp slice buffer: BSLICE b's, reused across slices (stays L3-resident)
    const size_t ZP_SLICE_BYTES =
        (size_t)BSLICE * T_ * PS * 256 * sizeof(bf16);      // 100663296
    bf16* zp  = (bf16*)ws;
    bf16* zT  = (bf16*)(ws + ZP_SLICE_BYTES + 8192);
    bf16* wTb = (bf16*)(ws + ZP_SLICE_BYTES + 8192 +
                        (size_t)M_GEMM * 256 * sizeof(bf16));

    transpose_z<<<dim3(T_ / 32, C_ / 32, B_), 256, 0, stream>>>(z, zT);
    pack_w<<<(N_GEMM * 256) / 256, 256, 0, stream>>>(w, wTb);

    for (int sl = 0; sl < NSLICE; ++sl) {
        int b_base = sl * BSLICE;
        gemm_zpred<<<(BSLICE * T_ / 128) * (N_GEMM / 128), 256, 0, stream>>>(
            zT, wTb, bias, zp, b_base);
        predict_kernel<<<(BSLICE * (T_ - OFFS)) / 32, 256, 0, stream>>>(
            zT, zp, neg, out, b_base);
    }
    hipMemsetAsync(out + NPRED, 0, NLAB * sizeof(float), stream);
}

// Round 7
// 151.952 us; speedup vs baseline: 1.0515x; 1.0515x over previous
//
#include <hip/hip_runtime.h>
#include <hip/hip_bf16.h>

// Problem constants
#define B_   16
#define C_   256
#define T_   2048
#define PS   12
#define NNEG 15
#define OFFS 16
#define COPIES 16

// Derived
#define M_GEMM (B_ * T_)        // 32768 rows (b,t)
#define N_GEMM (C_ * PS)        // 3072 cols (j = i*256 + o)
#define K_GEMM C_               // 256
#define NPRED 6225408           // sum_i (2032-i)*256
#define NLAB  389088

using bf16 = __hip_bfloat16;
typedef __attribute__((ext_vector_type(4))) float f32x4;
typedef __attribute__((ext_vector_type(8))) short bf16x8;

#define WAITVM(n) asm volatile("s_waitcnt vmcnt(" #n ")" ::: "memory")
#define GLL(src, dst)                                                        \
    __builtin_amdgcn_global_load_lds(                                        \
        (const __attribute__((address_space(1))) void*)(src),                \
        (__attribute__((address_space(3))) void*)(dst), 16, 0, 0)

// ---------------------------------------------------------------- transpose z
// z[b][c][t] f32  ->  zT[b][t][c] bf16
__global__ __launch_bounds__(256) void transpose_z(const float* __restrict__ z,
                                                   bf16* __restrict__ zT) {
    __shared__ float tile[32][33];
    int t0 = blockIdx.x * 32, c0 = blockIdx.y * 32, b = blockIdx.z;
    int col = threadIdx.x & 31, r = threadIdx.x >> 5;
    for (int rr = 0; rr < 4; ++rr) {
        int row = r + rr * 8;
        tile[row][col] = z[(size_t)(b * C_ + c0 + row) * T_ + t0 + col];
    }
    __syncthreads();
    for (int rr = 0; rr < 4; ++rr) {
        int row = r + rr * 8;
        zT[(size_t)(b * T_ + t0 + row) * C_ + c0 + col] =
            __float2bfloat16(tile[col][row]);
    }
}

// ---------------------------------------------------------------- pack weight
// w[c][o][i] f32 -> wTb[j][c] bf16 with j = i*256 + o
__global__ __launch_bounds__(256) void pack_w(const float* __restrict__ w,
                                              bf16* __restrict__ wTb) {
    int gid = blockIdx.x * 256 + threadIdx.x;
    int j = gid >> 8, c = gid & 255;
    int o = j & 255, i = j >> 8;
    wTb[gid] = __float2bfloat16(w[(size_t)c * (C_ * PS) + o * PS + i]);
}

// ---------------------------------------------------------------- z_pred GEMM
// 128x128 tile, 4 waves (2x2), BK=32, depth-3 counted-vmcnt LDS pipeline.
// (monolithic; identical to round-5 version, 73us known-good)
#define EPAD 136

__global__ __launch_bounds__(256) void gemm_zpred(const bf16* __restrict__ zT,
                                                  const bf16* __restrict__ wTb,
                                                  const float* __restrict__ bias,
                                                  bf16* __restrict__ zp) {
    __shared__ __align__(16) char smem[49152];
    bf16* lE = (bf16*)smem;

    int bid = (blockIdx.x & 7) * 768 + (blockIdx.x >> 3);
    int bn = bid % (N_GEMM / 128);
    int bm = bid / (N_GEMM / 128);
    int tid = threadIdx.x;
    int wid = tid >> 6, lane = tid & 63;
    int ln15 = lane & 15, kg = lane >> 4;
    int wm = (wid & 1) * 64, wn = (wid >> 1) * 64;
    int row0 = bm * 128, col0 = bn * 128;
    int i_step = col0 >> 8;
    int o0 = col0 & 255;

    int gsw = ((lane & 3) ^ ((lane >> 3) & 3)) * 8;
    int srow = wid * 16 + (lane >> 2);
    const bf16* srcA = zT + (size_t)(row0 + srow) * 256 + gsw;
    const bf16* srcB = wTb + (size_t)(col0 + srow) * 256 + gsw;

    int offA[4], offB[4];
#pragma unroll
    for (int mi = 0; mi < 4; ++mi) {
        int r = wm + mi * 16 + ln15;
        offA[mi] = r * 64 + ((kg ^ ((r >> 1) & 3)) * 16);
    }
#pragma unroll
    for (int ni = 0; ni < 4; ++ni) {
        int c = wn + ni * 16 + ln15;
        offB[ni] = 8192 + c * 64 + ((kg ^ ((c >> 1) & 3)) * 16);
    }

    f32x4 acc[4][4] = {};

#define STAGE(t, slot_base)                                                  \
    {                                                                        \
        char* d = smem + (slot_base) + wid * 1024;                           \
        const bf16* sa = srcA + (t) * 32;                                    \
        const bf16* sb2 = srcB + (t) * 32;                                   \
        GLL(sa, d);                                                          \
        GLL(sa + 64 * 256, d + 4096);                                        \
        GLL(sb2, d + 8192);                                                  \
        GLL(sb2 + 64 * 256, d + 12288);                                      \
    }

#define TILE_BODY(slot_base, VMN)                                            \
    {                                                                        \
        WAITVM(VMN);                                                         \
        __builtin_amdgcn_s_barrier();                                        \
        const char* sb = smem + (slot_base);                                 \
        bf16x8 af[4], bfr[4];                                                \
        _Pragma("unroll") for (int mi = 0; mi < 4; ++mi)                     \
            af[mi] = *(const bf16x8*)(sb + offA[mi]);                        \
        _Pragma("unroll") for (int ni = 0; ni < 4; ++ni)                     \
            bfr[ni] = *(const bf16x8*)(sb + offB[ni]);                       \
        asm volatile("s_waitcnt lgkmcnt(0)" ::: "memory");                   \
        __builtin_amdgcn_sched_barrier(0);                                   \
        __builtin_amdgcn_s_barrier();                                        \
        __builtin_amdgcn_s_setprio(1);                                       \
        _Pragma("unroll") for (int mi = 0; mi < 4; ++mi)                     \
            _Pragma("unroll") for (int ni = 0; ni < 4; ++ni)                 \
                acc[mi][ni] = __builtin_amdgcn_mfma_f32_16x16x32_bf16(       \
                    af[mi], bfr[ni], acc[mi][ni], 0, 0, 0);                  \
        __builtin_amdgcn_s_setprio(0);                                       \
    }

    STAGE(0, 0);
    STAGE(1, 16384);
    STAGE(2, 32768);  TILE_BODY(0, 8);
    STAGE(3, 0);      TILE_BODY(16384, 8);
    STAGE(4, 16384);  TILE_BODY(32768, 8);
    STAGE(5, 32768);  TILE_BODY(0, 8);
    STAGE(6, 0);      TILE_BODY(16384, 8);
    STAGE(7, 16384);  TILE_BODY(32768, 8);
                      TILE_BODY(0, 4);
                      TILE_BODY(16384, 0);

    __syncthreads();

    float bv[4];
#pragma unroll
    for (int ni = 0; ni < 4; ++ni) bv[ni] = bias[o0 + wn + ni * 16 + ln15];

#pragma unroll
    for (int mi = 0; mi < 4; ++mi)
#pragma unroll
        for (int ni = 0; ni < 4; ++ni) {
            int col_e = wn + ni * 16 + ln15;
#pragma unroll
            for (int r = 0; r < 4; ++r) {
                int row_e = wm + mi * 16 + kg * 4 + r;
                lE[row_e * EPAD + col_e] = __float2bfloat16(acc[mi][ni][r] + bv[ni]);
            }
        }

    __syncthreads();

#pragma unroll
    for (int e = 0; e < 8; ++e) {
        int row_e = e * 16 + (tid >> 4);
        int grow = row0 + row_e;
        int b = grow >> 11, t = grow & (T_ - 1);
        int s = t + OFFS + i_step;
        if (s < T_) {
            bf16x8 v = *(const bf16x8*)&lE[row_e * EPAD + (tid & 15) * 8];
            *(bf16x8*)(zp + ((size_t)(b * T_ + s) * PS + i_step) * 256 + o0 +
                       (tid & 15) * 8) = v;
        }
    }
#undef STAGE
#undef TILE_BODY
}

// ---------------------------------------------------------------- predictions
// One wave per (b,s) per iteration; 8 iters; 2 LDS slots (A 16x512B, zp
// 12x512B) staged via global_load_lds with COUNTED vmcnt. Round-7 fix: all
// neg-row indices preloaded in the prologue (two int4 per lane), so the loop
// body has NO dependent VMEM loads -> no hidden vmcnt(0) drain; out stored
// as one float4 (1 VMEM op) so vmcnt bookkeeping is exact:
// steady outstanding = 14 GLL(next slot) + 1 store -> WAITVM(15).
__global__ __launch_bounds__(256) void predict_kernel(
    const bf16* __restrict__ zT, const bf16* __restrict__ zp,
    const int* __restrict__ neg, float* __restrict__ out) {
    __shared__ __align__(16) char psm[131072];
    int tid = threadIdx.x;
    int wid = tid >> 6, lane = tid & 63;
    int ln15 = lane & 15, kg = lane >> 4;
    char* my = psm + wid * 32768;           // wave-private: 2 slots x 16KB
    int base_gi = (blockIdx.x * 4 + wid) * 8;
    int b = base_gi / (T_ - OFFS);          // 8 | 2032: whole wave shares b
    int s_base = OFFS + base_gi % (T_ - OFFS);

    const char* zTb = (const char*)zT;
    const char* zpb = (const char*)zp;

    // ---- prologue: preload all neg rows for the wave's 8 (b,s) pairs
    int srcrow[8];
    if (lane == 0) {
#pragma unroll
        for (int it = 0; it < 8; ++it) srcrow[it] = b * T_ + s_base + it;
    } else if (lane < 16) {
        const int* np = neg + b * (NNEG * T_) + (lane - 1) * T_ + s_base;
        int4 n0 = *(const int4*)np;
        int4 n1 = *(const int4*)(np + 4);
        srcrow[0] = n0.x; srcrow[1] = n0.y; srcrow[2] = n0.z; srcrow[3] = n0.w;
        srcrow[4] = n1.x; srcrow[5] = n1.y; srcrow[6] = n1.z; srcrow[7] = n1.w;
    } else {
#pragma unroll
        for (int it = 0; it < 8; ++it) srcrow[it] = 0;
    }

    auto stage = [&](int it, int slot, int sr) {
        int s = s_base + it;
        char* dst = my + slot * 16384;
        int half = lane >> 5;
        int g31 = lane & 31;
#pragma unroll
        for (int j = 0; j < 8; ++j) {
            int r0 = __shfl(sr, 2 * j);
            int r1 = __shfl(sr, 2 * j + 1);
            int row = half ? r1 : r0;
            int n = 2 * j + half;
            GLL(zTb + (size_t)row * 512 + ((g31 ^ (n & 7)) << 4),
                dst + j * 1024);
        }
        size_t zoff = (size_t)(b * T_ + s) * (PS * 512);
#pragma unroll
        for (int j = 0; j < 6; ++j) {
            int i0 = 2 * j + half;
            GLL(zpb + zoff + i0 * 512 + ((g31 ^ (i0 & 7)) << 4),
                dst + 8192 + j * 1024);
        }
    };

    auto compute = [&](int it, int slot) {
        const char* sb = my + slot * 16384;
        int ii = ln15 < 12 ? ln15 : 0;      // dup col 0 for pad lanes (bcast)
        bf16x8 af[8], bfr[8];
#pragma unroll
        for (int kk = 0; kk < 8; ++kk) {
            int g = kk * 4 + kg;
            af[kk] = *(const bf16x8*)(sb + ln15 * 512 + ((g ^ (ln15 & 7)) << 4));
            bfr[kk] = *(const bf16x8*)(sb + 8192 + ii * 512 + ((g ^ (ii & 7)) << 4));
        }
        // frags secured in regs before this slot is restaged
        asm volatile("s_waitcnt lgkmcnt(0)" ::: "memory");
        __builtin_amdgcn_sched_barrier(0);
        if (it + 2 < 8) stage(it + 2, slot, srcrow[it + 2 < 8 ? it + 2 : 0]);

        f32x4 acc = {0.f, 0.f, 0.f, 0.f};
#pragma unroll
        for (int kk = 0; kk < 8; ++kk)
            acc = __builtin_amdgcn_mfma_f32_16x16x32_bf16(af[kk], bfr[kk], acc,
                                                          0, 0, 0);

        int s = s_base + it;
        int i = ln15;
        int imax = s - OFFS; if (imax > PS - 1) imax = PS - 1;
        if (i <= imax) {
            int t = s - OFFS - i;
            int base_i = 256 * ((T_ - OFFS) * i - (i * (i - 1)) / 2);
            float* o = out + base_i + (t * B_ + b) * COPIES + kg * 4;
            *(f32x4*)o = acc;               // single 16B store (1 VMEM op)
        }
    };

    stage(0, 0, srcrow[0]);
    stage(1, 1, srcrow[1]);

    // vmcnt ledger (FIFO): it0: 28 out -> WAIT(14) completes GLL(0).
    // steady: GLL(it)14 [+store] + GLL(it+1)14 + store -> WAIT(15) completes
    // exactly through GLL(it). drain it7: GLL(7)14 + store(6) -> WAIT(1).
    WAITVM(14); compute(0, 0);
    WAITVM(15); compute(1, 1);
    WAITVM(15); compute(2, 0);
    WAITVM(15); compute(3, 1);
    WAITVM(15); compute(4, 0);
    WAITVM(15); compute(5, 1);
    WAITVM(15); compute(6, 0);
    WAITVM(1);  compute(7, 1);
}

// ---------------------------------------------------------------- launch
extern "C" void kernel_launch(void* const* d_in, const int* in_sizes, int n_in,
                              void* d_out, int out_size, void* d_ws, size_t ws_size,
                              hipStream_t stream) {
    const float* z    = (const float*)d_in[0];
    const float* w    = (const float*)d_in[1];
    const float* bias = (const float*)d_in[2];
    const int*   neg  = (const int*)d_in[3];
    float* out = (float*)d_out;

    char* ws = (char*)d_ws;
    const size_t ZP_BYTES = (size_t)B_ * T_ * PS * 256 * sizeof(bf16);
    bf16* zp  = (bf16*)ws;
    bf16* zT  = (bf16*)(ws + ZP_BYTES + 8192);
    bf16* wTb = (bf16*)(ws + ZP_BYTES + 8192 + (size_t)M_GEMM * 256 * sizeof(bf16));

    transpose_z<<<dim3(T_ / 32, C_ / 32, B_), 256, 0, stream>>>(z, zT);
    pack_w<<<(N_GEMM * 256) / 256, 256, 0, stream>>>(w, wTb);
    gemm_zpred<<<(M_GEMM / 128) * (N_GEMM / 128), 256, 0, stream>>>(zT, wTb, bias, zp);
    predict_kernel<<<(B_ * (T_ - OFFS)) / 32, 256, 0, stream>>>(zT, zp, neg, out);
    hipMemsetAsync(out + NPRED, 0, NLAB * sizeof(float), stream);
}